// Round 4
// baseline (686.463 us; speedup 1.0000x reference)
//
#include <hip/hip_runtime.h>
#include <hip/hip_bf16.h>
#include <math.h>

// Problem constants: B=2, C=128, T=512, F=64 -> N=B*F=128 sequences, NT=65536 rows.
// GRU: G=4 groups, D=32, 3D=96. MHA: H=4 heads, Dh=32, window=100.
// Workspace layout (needs ~100.8 MB):
//   seq  fp32 [65536][128]  @ 0          (33,554,432 B)  residual stream
//   tmpb bf16 [65536][128]  @ 33554432   (16,777,216 B)  ln1/ln2/attn-out
//   big  bf16 [65536][384]  @ 50331648   (50,331,648 B)  xp (grouped: [(n,t,g)][96]) then qkv
//   wbuf bf16 weights       @ 100663296  (~137 KB)

typedef __attribute__((ext_vector_type(8))) short short8;
typedef __attribute__((ext_vector_type(4))) float f32x4;

__device__ __forceinline__ float bflo(unsigned int u) { return __uint_as_float(u << 16); }
__device__ __forceinline__ float bfhi(unsigned int u) { return __uint_as_float(u & 0xffff0000u); }
__device__ __forceinline__ float bf2f(unsigned short u) { return __uint_as_float(((unsigned int)u) << 16); }
__device__ __forceinline__ unsigned short f2bf(float f) {
  __hip_bfloat16 h = __float2bfloat16(f);
  return *reinterpret_cast<unsigned short*>(&h);
}

// ---------------- weight fp32 -> bf16 ----------------
__global__ void cvt_kernel(const float* __restrict__ s, unsigned short* __restrict__ d, int n) {
  int i = blockIdx.x * 256 + threadIdx.x;
  if (i < n) d[i] = f2bf(s[i]);
}

// ---------------- transpose x[B,C,T,F] -> seq[(b*64+f)][t][c] ----------------
__global__ __launch_bounds__(256) void transpose_in_kernel(const float* __restrict__ x, float* __restrict__ seq) {
  __shared__ float tile[128 * 65];
  int b = blockIdx.x >> 9;
  int t = blockIdx.x & 511;
  for (int i = threadIdx.x; i < 128 * 64; i += 256) {
    int c = i >> 6, f = i & 63;
    tile[c * 65 + f] = x[(((size_t)(b * 128 + c)) * 512 + t) * 64 + f];
  }
  __syncthreads();
  for (int i = threadIdx.x; i < 64 * 128; i += 256) {
    int f = i >> 7, c = i & 127;
    seq[(((size_t)(b * 64 + f)) * 512 + t) * 128 + c] = tile[c * 65 + f];
  }
}

__global__ __launch_bounds__(256) void transpose_out_kernel(const float* __restrict__ seq, float* __restrict__ out) {
  __shared__ float tile[128 * 65];
  int b = blockIdx.x >> 9;
  int t = blockIdx.x & 511;
  for (int i = threadIdx.x; i < 64 * 128; i += 256) {
    int f = i >> 7, c = i & 127;
    tile[c * 65 + f] = seq[(((size_t)(b * 64 + f)) * 512 + t) * 128 + c];
  }
  __syncthreads();
  for (int i = threadIdx.x; i < 128 * 64; i += 256) {
    int c = i >> 6, f = i & 63;
    out[(((size_t)(b * 128 + c)) * 512 + t) * 64 + f] = tile[c * 65 + f];
  }
}

// ---------------- layernorm over C=128, fp32 in -> bf16 out ----------------
__global__ __launch_bounds__(256) void ln_kernel(const float* __restrict__ in, const float* __restrict__ g,
                                                 const float* __restrict__ b, unsigned short* __restrict__ out) {
  int row = blockIdx.x * 4 + (threadIdx.x >> 6);
  int lane = threadIdx.x & 63;
  float2 v = ((const float2*)(in + (size_t)row * 128))[lane];
  float s = v.x + v.y, ss = v.x * v.x + v.y * v.y;
  #pragma unroll
  for (int off = 32; off > 0; off >>= 1) {
    s += __shfl_xor(s, off);
    ss += __shfl_xor(ss, off);
  }
  float mean = s * (1.f / 128.f);
  float var = ss * (1.f / 128.f) - mean * mean;
  float rs = rsqrtf(var + 1e-5f);
  float2 gg = ((const float2*)g)[lane];
  float2 bb = ((const float2*)b)[lane];
  float o0 = (v.x - mean) * rs * gg.x + bb.x;
  float o1 = (v.y - mean) * rs * gg.y + bb.y;
  unsigned int packed = ((unsigned int)f2bf(o1) << 16) | (unsigned int)f2bf(o0);
  ((unsigned int*)(out + (size_t)row * 128))[lane] = packed;
}

// ---------------- MFMA GEMM: out[m][n] (+)= sum_k A[m][k]*W[n][k] + bias[n] ----------------
// A bf16 [M][K] (M = gridDim.x*128), W bf16 [Ncols][K]. MODE 0: store bf16 (stride Ncols).
// MODE 1: outF[m*128+n] += v (fp32).
template <int K, int MODE>
__global__ __launch_bounds__(256) void gemm_mfma(const unsigned short* __restrict__ A,
                                                 const unsigned short* __restrict__ W,
                                                 const float* __restrict__ bias,
                                                 unsigned short* __restrict__ outB,
                                                 float* __restrict__ outF, int Ncols) {
  const int tid = threadIdx.x;
  const int wave = tid >> 6, lane = tid & 63;
  const int wy = wave >> 1, wx = wave & 1;
  const int lr = lane & 15, lq = lane >> 4;
  const int m0 = blockIdx.x * 128 + wy * 64;
  const int n0 = blockIdx.y * 128 + wx * 64;

  f32x4 acc[4][4];
  #pragma unroll
  for (int i = 0; i < 4; ++i)
    #pragma unroll
    for (int j = 0; j < 4; ++j) acc[i][j] = f32x4{0.f, 0.f, 0.f, 0.f};

  const short8 zfrag = short8{0, 0, 0, 0, 0, 0, 0, 0};

  #pragma unroll
  for (int kk = 0; kk < K; kk += 32) {
    short8 af[4], bfq[4];
    #pragma unroll
    for (int i = 0; i < 4; ++i)
      af[i] = *(const short8*)(A + (size_t)(m0 + i * 16 + lr) * K + kk + lq * 8);
    #pragma unroll
    for (int j = 0; j < 4; ++j) {
      int wr = n0 + j * 16 + lr;
      bfq[j] = (wr < Ncols) ? *(const short8*)(W + (size_t)wr * K + kk + lq * 8) : zfrag;
    }
    #pragma unroll
    for (int i = 0; i < 4; ++i)
      #pragma unroll
      for (int j = 0; j < 4; ++j)
        acc[i][j] = __builtin_amdgcn_mfma_f32_16x16x32_bf16(af[i], bfq[j], acc[i][j], 0, 0, 0);
  }

  #pragma unroll
  for (int j = 0; j < 4; ++j) {
    int col = n0 + j * 16 + lr;
    if (col < Ncols) {
      float bb = bias[col];
      #pragma unroll
      for (int i = 0; i < 4; ++i) {
        #pragma unroll
        for (int r = 0; r < 4; ++r) {
          int row = m0 + i * 16 + lq * 4 + r;
          float v = acc[i][j][r] + bb;
          if (MODE == 0)
            outB[(size_t)row * Ncols + col] = f2bf(v);
          else
            outF[(size_t)row * 128 + col] += v;
        }
      }
    }
  }
}

// ---------------- grouped GRU scan over T=512 — 1 chain/wave, K-split, bpermute h ----------------
// 512 blocks x 64 threads (1 wave, 1 chain). Lane (half=l>>5, d=l&31) computes the k-half
// [half*16, half*16+16) of the three gate dot-products for hidden dim d. 48 weights/lane, PINNED
// in VGPRs via asm (round-3 evidence: VGPR_Count=84 proved the allocator rematerializes
// loop-invariant weight loads inside the serial loop — the asm makes the values opaque so they
// must stay live). Halves merge via __shfl_xor(.,32); h broadcast for the next step is 16
// ds_bpermute pulls (no LDS storage -> no write->lgkmcnt->read turnaround, no barriers).
__global__ __launch_bounds__(64, 1) void gru_kernel(const unsigned short* __restrict__ xp,
                                                    const float* __restrict__ whh,
                                                    const float* __restrict__ bhh,
                                                    float* __restrict__ seq) {
  const int l = threadIdx.x;
  const int half = l >> 5, d = l & 31;
  const int chain = blockIdx.x;         // 0..511
  const int n = chain >> 2, g = chain & 3;
  const int k0 = half * 16;

  // 48 weights: w[0..15]=whh_r[d][k0+j], w[16..31]=whh_z, w[32..47]=whh_n
  float w[48];
  #pragma unroll
  for (int u = 0; u < 4; ++u) {
    float4 a = *(const float4*)(whh + (size_t)d * 32 + k0 + u * 4);
    float4 b = *(const float4*)(whh + (size_t)(32 + d) * 32 + k0 + u * 4);
    float4 c = *(const float4*)(whh + (size_t)(64 + d) * 32 + k0 + u * 4);
    w[u * 4 + 0] = a.x;  w[u * 4 + 1] = a.y;  w[u * 4 + 2] = a.z;  w[u * 4 + 3] = a.w;
    w[16 + u * 4 + 0] = b.x; w[16 + u * 4 + 1] = b.y; w[16 + u * 4 + 2] = b.z; w[16 + u * 4 + 3] = b.w;
    w[32 + u * 4 + 0] = c.x; w[32 + u * 4 + 1] = c.y; w[32 + u * 4 + 2] = c.z; w[32 + u * 4 + 3] = c.w;
  }
  #pragma unroll
  for (int i = 0; i < 48; ++i) asm volatile("" : "+v"(w[i]));  // defeat remat: pin in VGPRs

  const float br = bhh[d], bz = bhh[32 + d], bn = bhh[64 + d];

  // xp row for this chain at step t: xp[((n*512+t)*4+g)*96 + {d, 32+d, 64+d}]
  const unsigned short* xb = xp + ((size_t)(n * 512) * 4 + g) * 96;
  // seq target (lanes 0..31 store): seq[(n*512+t)*128 + g*32 + d]
  float* sb = seq + (size_t)(n * 512) * 128 + g * 32 + d;

  unsigned short pr[4], pz[4], pn[4];
  float psv[4];
  #pragma unroll
  for (int p = 0; p < 4; ++p) {
    const unsigned short* xr_ = xb + (size_t)p * 384;
    pr[p] = xr_[d]; pz[p] = xr_[32 + d]; pn[p] = xr_[64 + d];
    psv[p] = sb[(size_t)p * 128];
  }

  float hnew = 0.f;                 // lane's h_d (valid in lanes 0..31; upper half unused copy)
  const int pbase = half * 64;      // bpermute byte base: lower half pulls lanes 0..15, upper 16..31

  for (int t0 = 0; t0 < 512; t0 += 4) {
    #pragma unroll
    for (int p = 0; p < 4; ++p) {
      const int t = t0 + p;

      // broadcast h[k0+j] from lane (k0+j) (lower-half copies hold h)
      float hj[16];
      #pragma unroll
      for (int j = 0; j < 16; ++j)
        hj[j] = __int_as_float(__builtin_amdgcn_ds_bpermute(pbase + 4 * j, __float_as_int(hnew)));

      float ar = 0.f, az = 0.f, an = 0.f;
      #pragma unroll
      for (int j = 0; j < 16; ++j) {
        ar = fmaf(w[j], hj[j], ar);
        az = fmaf(w[16 + j], hj[j], az);
        an = fmaf(w[32 + j], hj[j], an);
      }
      // merge k-halves (both halves end with the full sums)
      ar += __shfl_xor(ar, 32);
      az += __shfl_xor(az, 32);
      an += __shfl_xor(an, 32);
      float accr = ar + br, accz = az + bz, accn = an + bn;

      float xr = bf2f(pr[p]), xz = bf2f(pz[p]), xn = bf2f(pn[p]);
      float sv0 = psv[p];

      if (t + 4 < 512) {  // prefetch t+4 into slot p (stays in flight)
        const unsigned short* xr_ = xb + (size_t)(t + 4) * 384;
        pr[p] = xr_[d]; pz[p] = xr_[32 + d]; pn[p] = xr_[64 + d];
        psv[p] = sb[(size_t)(t + 4) * 128];
      }

      float r = 1.f / (1.f + __expf(-(xr + accr)));
      float z = 1.f / (1.f + __expf(-(xz + accz)));
      float e2 = __expf(2.f * (xn + r * accn));
      float nn = 1.f - 2.f / (e2 + 1.f);  // tanh, saturates cleanly at +/-1
      hnew = z * (hnew - nn) + nn;

      if (half == 0) sb[(size_t)t * 128] = sv0 + hnew;
    }
  }
}

// ---------------- windowed causal attention (scalar online softmax) ----------------
// grid (T/64=8, H=4, N=128), 128 threads = 32 q-pairs x 4 key-slices.
// qkv bf16 [n*512+t][384]: q @ h*32, k @ 128+h*32, v @ 256+h*32. out bf16 [n*512+t][128].
#define WCAP 164
__global__ __launch_bounds__(128) void attn_kernel(const unsigned short* __restrict__ qkv,
                                                   unsigned short* __restrict__ outp) {
  const int qbase = blockIdx.x * 64;
  const int h = blockIdx.y;
  const int n = blockIdx.z;
  const int tid = threadIdx.x;
  const int qp = tid >> 2, s = tid & 3;
  const int ws0 = max(0, qbase - 100);
  const int cnt = qbase + 64 - ws0;  // <= 164

  __shared__ unsigned int kl[WCAP * 20];
  __shared__ unsigned int vl[WCAP * 20];

  for (int i = tid; i < cnt * 16; i += 128) {
    int row = i >> 4, u = i & 15;
    size_t base = ((size_t)(n * 512 + ws0 + row)) * 384;
    kl[row * 20 + u] = ((const unsigned int*)(qkv + base + 128 + h * 32))[u];
    vl[row * 20 + u] = ((const unsigned int*)(qkv + base + 256 + h * 32))[u];
  }

  const int tqa = qbase + qp * 2, tqb = tqa + 1;
  float qv[2][32];
  {
    const unsigned int* qsa = (const unsigned int*)(qkv + ((size_t)(n * 512 + tqa)) * 384 + h * 32);
    const unsigned int* qsb = (const unsigned int*)(qkv + ((size_t)(n * 512 + tqb)) * 384 + h * 32);
    #pragma unroll
    for (int u = 0; u < 16; ++u) {
      unsigned int a = qsa[u], b = qsb[u];
      qv[0][2 * u] = bflo(a); qv[0][2 * u + 1] = bfhi(a);
      qv[1][2 * u] = bflo(b); qv[1][2 * u + 1] = bfhi(b);
    }
  }
  __syncthreads();

  float m[2] = {-INFINITY, -INFINITY}, l[2] = {0.f, 0.f};
  float o[2][32];
  #pragma unroll
  for (int d = 0; d < 32; ++d) { o[0][d] = 0.f; o[1][d] = 0.f; }

  const float scale = 0.17677669529663687f;  // 1/sqrt(32)
  const int iters = (cnt + 3) >> 2;

  for (int c = 0; c < iters; ++c) {
    int j = (c << 2) + s;
    int tk = ws0 + j;
    bool okv = (j < cnt);
    bool oka = okv && (tk <= tqa) && (tk + 100 >= tqa);
    bool okb = okv && (tk <= tqb) && (tk + 100 >= tqb);
    if (oka || okb) {
      float sa = 0.f, sb = 0.f;
      #pragma unroll
      for (int u = 0; u < 4; ++u) {
        uint4 kk = *(const uint4*)&kl[j * 20 + u * 4];
        float f0 = bflo(kk.x), f1 = bfhi(kk.x), f2 = bflo(kk.y), f3 = bfhi(kk.y);
        float f4 = bflo(kk.z), f5 = bfhi(kk.z), f6 = bflo(kk.w), f7 = bfhi(kk.w);
        int ee = u * 8;
        sa += qv[0][ee] * f0 + qv[0][ee + 1] * f1 + qv[0][ee + 2] * f2 + qv[0][ee + 3] * f3 +
              qv[0][ee + 4] * f4 + qv[0][ee + 5] * f5 + qv[0][ee + 6] * f6 + qv[0][ee + 7] * f7;
        sb += qv[1][ee] * f0 + qv[1][ee + 1] * f1 + qv[1][ee + 2] * f2 + qv[1][ee + 3] * f3 +
              qv[1][ee + 4] * f4 + qv[1][ee + 5] * f5 + qv[1][ee + 6] * f6 + qv[1][ee + 7] * f7;
      }
      sa *= scale; sb *= scale;
      float mna = oka ? fmaxf(m[0], sa) : m[0];
      float mnb = okb ? fmaxf(m[1], sb) : m[1];
      float ca = oka ? __expf(m[0] - mna) : 1.f;
      float cb = okb ? __expf(m[1] - mnb) : 1.f;
      float pa = oka ? __expf(sa - mna) : 0.f;
      float pb = okb ? __expf(sb - mnb) : 0.f;
      m[0] = mna; m[1] = mnb;
      l[0] = l[0] * ca + pa; l[1] = l[1] * cb + pb;
      #pragma unroll
      for (int u = 0; u < 4; ++u) {
        uint4 vvv = *(const uint4*)&vl[j * 20 + u * 4];
        float f0 = bflo(vvv.x), f1 = bfhi(vvv.x), f2 = bflo(vvv.y), f3 = bfhi(vvv.y);
        float f4 = bflo(vvv.z), f5 = bfhi(vvv.z), f6 = bflo(vvv.w), f7 = bfhi(vvv.w);
        int ee = u * 8;
        o[0][ee] = o[0][ee] * ca + pa * f0;       o[1][ee] = o[1][ee] * cb + pb * f0;
        o[0][ee + 1] = o[0][ee + 1] * ca + pa * f1; o[1][ee + 1] = o[1][ee + 1] * cb + pb * f1;
        o[0][ee + 2] = o[0][ee + 2] * ca + pa * f2; o[1][ee + 2] = o[1][ee + 2] * cb + pb * f2;
        o[0][ee + 3] = o[0][ee + 3] * ca + pa * f3; o[1][ee + 3] = o[1][ee + 3] * cb + pb * f3;
        o[0][ee + 4] = o[0][ee + 4] * ca + pa * f4; o[1][ee + 4] = o[1][ee + 4] * cb + pb * f4;
        o[0][ee + 5] = o[0][ee + 5] * ca + pa * f5; o[1][ee + 5] = o[1][ee + 5] * cb + pb * f5;
        o[0][ee + 6] = o[0][ee + 6] * ca + pa * f6; o[1][ee + 6] = o[1][ee + 6] * cb + pb * f6;
        o[0][ee + 7] = o[0][ee + 7] * ca + pa * f7; o[1][ee + 7] = o[1][ee + 7] * cb + pb * f7;
      }
    }
  }

  // merge the 4 key-slices (lanes 4*qp .. 4*qp+3, same wave) via shfl butterflies
  #pragma unroll
  for (int qi = 0; qi < 2; ++qi) {
    float mm = m[qi];
    mm = fmaxf(mm, __shfl_xor(mm, 1));
    mm = fmaxf(mm, __shfl_xor(mm, 2));
    float cr = __expf(m[qi] - mm);  // exp(-inf - finite) = 0 for empty slices
    float ll = l[qi] * cr;
    ll += __shfl_xor(ll, 1);
    ll += __shfl_xor(ll, 2);
    float rl = 1.f / ll;
    int tq = (qi == 0) ? tqa : tqb;
    size_t ob = ((size_t)(n * 512 + tq)) * 128 + h * 32;
    #pragma unroll
    for (int d = 0; d < 32; ++d) {
      float od = o[qi][d] * cr;
      od += __shfl_xor(od, 1);
      od += __shfl_xor(od, 2);
      if (s == 0) outp[ob + d] = f2bf(od * rl);
    }
  }
}

// ---------------- host launcher ----------------
extern "C" void kernel_launch(void* const* d_in, const int* in_sizes, int n_in,
                              void* d_out, int out_size, void* d_ws, size_t ws_size,
                              hipStream_t stream) {
  const float* x      = (const float*)d_in[0];
  const float* ln1_g  = (const float*)d_in[1];
  const float* ln1_b  = (const float*)d_in[2];
  const float* wih    = (const float*)d_in[3];
  const float* whh    = (const float*)d_in[4];
  const float* bih    = (const float*)d_in[5];
  const float* bhh    = (const float*)d_in[6];
  const float* ln2_g  = (const float*)d_in[7];
  const float* ln2_b  = (const float*)d_in[8];
  const float* inw    = (const float*)d_in[9];
  const float* inb    = (const float*)d_in[10];
  const float* outw   = (const float*)d_in[11];
  const float* outb   = (const float*)d_in[12];

  char* ws = (char*)d_ws;
  float*          seq   = (float*)ws;                             // 33,554,432 B
  unsigned short* tmpb  = (unsigned short*)(ws + 33554432);       // 16,777,216 B
  unsigned short* big   = (unsigned short*)(ws + 50331648);       // 50,331,648 B
  unsigned short* wih_b = (unsigned short*)(ws + 100663296);      // 3072 elems
  unsigned short* inw_b = wih_b + 3072;                           // 49152 elems
  unsigned short* outw_b = inw_b + 49152;                         // 16384 elems

  cvt_kernel<<<12, 256, 0, stream>>>(wih, wih_b, 3072);
  cvt_kernel<<<192, 256, 0, stream>>>(inw, inw_b, 49152);
  cvt_kernel<<<64, 256, 0, stream>>>(outw, outw_b, 16384);

  // x -> seq (residual stream)
  transpose_in_kernel<<<1024, 256, 0, stream>>>(x, seq);

  // ln1 -> tmpb (bf16), grouped view [262144][32]
  ln_kernel<<<16384, 256, 0, stream>>>(seq, ln1_g, ln1_b, tmpb);

  // GRU input projection: [262144][32] x [96][32]^T -> big [(n,t,g)][96]
  gemm_mfma<32, 0><<<dim3(2048, 1), 256, 0, stream>>>(tmpb, wih_b, bih, big, nullptr, 96);

  // GRU scan, seq += h_t  (1 chain per single-wave block)
  gru_kernel<<<512, 64, 0, stream>>>(big, whh, bhh, seq);

  // ln2 -> tmpb
  ln_kernel<<<16384, 256, 0, stream>>>(seq, ln2_g, ln2_b, tmpb);

  // QKV projection: [65536][128] x [384][128]^T -> big [65536][384]
  gemm_mfma<128, 0><<<dim3(512, 3), 256, 0, stream>>>(tmpb, inw_b, inb, big, nullptr, 384);

  // attention -> tmpb (bf16)
  attn_kernel<<<dim3(8, 4, 128), 128, 0, stream>>>(big, tmpb);

  // out projection, seq += attn @ Wo^T + bo
  gemm_mfma<128, 1><<<dim3(512, 1), 256, 0, stream>>>(tmpb, outw_b, outb, nullptr, seq, 128);

  // seq -> d_out
  transpose_out_kernel<<<1024, 256, 0, stream>>>(seq, (float*)d_out);
}

// Round 5
// 685.075 us; speedup vs baseline: 1.0020x; 1.0020x over previous
//
#include <hip/hip_runtime.h>
#include <hip/hip_bf16.h>
#include <math.h>

// Problem constants: B=2, C=128, T=512, F=64 -> N=B*F=128 sequences, NT=65536 rows.
// GRU: G=4 groups, D=32, 3D=96. MHA: H=4 heads, Dh=32, window=100.
// Workspace layout (needs ~100.8 MB):
//   seq  fp32 [65536][128]  @ 0          (33,554,432 B)  residual stream
//   tmpb bf16 [65536][128]  @ 33554432   (16,777,216 B)  ln1/ln2/attn-out
//   big  bf16 [65536][384]  @ 50331648   (50,331,648 B)  xp (grouped: [(n,t,g)][96]) then qkv
//   wbuf bf16 weights       @ 100663296  (~137 KB)

typedef __attribute__((ext_vector_type(8))) short short8;
typedef __attribute__((ext_vector_type(4))) float f32x4;

__device__ __forceinline__ float bflo(unsigned int u) { return __uint_as_float(u << 16); }
__device__ __forceinline__ float bfhi(unsigned int u) { return __uint_as_float(u & 0xffff0000u); }
__device__ __forceinline__ float bf2f(unsigned short u) { return __uint_as_float(((unsigned int)u) << 16); }
__device__ __forceinline__ unsigned short f2bf(float f) {
  __hip_bfloat16 h = __float2bfloat16(f);
  return *reinterpret_cast<unsigned short*>(&h);
}

// ---------------- weight fp32 -> bf16 ----------------
__global__ void cvt_kernel(const float* __restrict__ s, unsigned short* __restrict__ d, int n) {
  int i = blockIdx.x * 256 + threadIdx.x;
  if (i < n) d[i] = f2bf(s[i]);
}

// ---------------- transpose x[B,C,T,F] -> seq[(b*64+f)][t][c] ----------------
__global__ __launch_bounds__(256) void transpose_in_kernel(const float* __restrict__ x, float* __restrict__ seq) {
  __shared__ float tile[128 * 65];
  int b = blockIdx.x >> 9;
  int t = blockIdx.x & 511;
  for (int i = threadIdx.x; i < 128 * 64; i += 256) {
    int c = i >> 6, f = i & 63;
    tile[c * 65 + f] = x[(((size_t)(b * 128 + c)) * 512 + t) * 64 + f];
  }
  __syncthreads();
  for (int i = threadIdx.x; i < 64 * 128; i += 256) {
    int f = i >> 7, c = i & 127;
    seq[(((size_t)(b * 64 + f)) * 512 + t) * 128 + c] = tile[c * 65 + f];
  }
}

__global__ __launch_bounds__(256) void transpose_out_kernel(const float* __restrict__ seq, float* __restrict__ out) {
  __shared__ float tile[128 * 65];
  int b = blockIdx.x >> 9;
  int t = blockIdx.x & 511;
  for (int i = threadIdx.x; i < 64 * 128; i += 256) {
    int f = i >> 7, c = i & 127;
    tile[c * 65 + f] = seq[(((size_t)(b * 64 + f)) * 512 + t) * 128 + c];
  }
  __syncthreads();
  for (int i = threadIdx.x; i < 128 * 64; i += 256) {
    int c = i >> 6, f = i & 63;
    out[(((size_t)(b * 128 + c)) * 512 + t) * 64 + f] = tile[c * 65 + f];
  }
}

// ---------------- layernorm over C=128, fp32 in -> bf16 out ----------------
__global__ __launch_bounds__(256) void ln_kernel(const float* __restrict__ in, const float* __restrict__ g,
                                                 const float* __restrict__ b, unsigned short* __restrict__ out) {
  int row = blockIdx.x * 4 + (threadIdx.x >> 6);
  int lane = threadIdx.x & 63;
  float2 v = ((const float2*)(in + (size_t)row * 128))[lane];
  float s = v.x + v.y, ss = v.x * v.x + v.y * v.y;
  #pragma unroll
  for (int off = 32; off > 0; off >>= 1) {
    s += __shfl_xor(s, off);
    ss += __shfl_xor(ss, off);
  }
  float mean = s * (1.f / 128.f);
  float var = ss * (1.f / 128.f) - mean * mean;
  float rs = rsqrtf(var + 1e-5f);
  float2 gg = ((const float2*)g)[lane];
  float2 bb = ((const float2*)b)[lane];
  float o0 = (v.x - mean) * rs * gg.x + bb.x;
  float o1 = (v.y - mean) * rs * gg.y + bb.y;
  unsigned int packed = ((unsigned int)f2bf(o1) << 16) | (unsigned int)f2bf(o0);
  ((unsigned int*)(out + (size_t)row * 128))[lane] = packed;
}

// ---------------- MFMA GEMM: out[m][n] (+)= sum_k A[m][k]*W[n][k] + bias[n] ----------------
// A bf16 [M][K] (M = gridDim.x*128), W bf16 [Ncols][K]. MODE 0: store bf16 (stride Ncols).
// MODE 1: outF[m*128+n] += v (fp32).
template <int K, int MODE>
__global__ __launch_bounds__(256) void gemm_mfma(const unsigned short* __restrict__ A,
                                                 const unsigned short* __restrict__ W,
                                                 const float* __restrict__ bias,
                                                 unsigned short* __restrict__ outB,
                                                 float* __restrict__ outF, int Ncols) {
  const int tid = threadIdx.x;
  const int wave = tid >> 6, lane = tid & 63;
  const int wy = wave >> 1, wx = wave & 1;
  const int lr = lane & 15, lq = lane >> 4;
  const int m0 = blockIdx.x * 128 + wy * 64;
  const int n0 = blockIdx.y * 128 + wx * 64;

  f32x4 acc[4][4];
  #pragma unroll
  for (int i = 0; i < 4; ++i)
    #pragma unroll
    for (int j = 0; j < 4; ++j) acc[i][j] = f32x4{0.f, 0.f, 0.f, 0.f};

  const short8 zfrag = short8{0, 0, 0, 0, 0, 0, 0, 0};

  #pragma unroll
  for (int kk = 0; kk < K; kk += 32) {
    short8 af[4], bfq[4];
    #pragma unroll
    for (int i = 0; i < 4; ++i)
      af[i] = *(const short8*)(A + (size_t)(m0 + i * 16 + lr) * K + kk + lq * 8);
    #pragma unroll
    for (int j = 0; j < 4; ++j) {
      int wr = n0 + j * 16 + lr;
      bfq[j] = (wr < Ncols) ? *(const short8*)(W + (size_t)wr * K + kk + lq * 8) : zfrag;
    }
    #pragma unroll
    for (int i = 0; i < 4; ++i)
      #pragma unroll
      for (int j = 0; j < 4; ++j)
        acc[i][j] = __builtin_amdgcn_mfma_f32_16x16x32_bf16(af[i], bfq[j], acc[i][j], 0, 0, 0);
  }

  #pragma unroll
  for (int j = 0; j < 4; ++j) {
    int col = n0 + j * 16 + lr;
    if (col < Ncols) {
      float bb = bias[col];
      #pragma unroll
      for (int i = 0; i < 4; ++i) {
        #pragma unroll
        for (int r = 0; r < 4; ++r) {
          int row = m0 + i * 16 + lq * 4 + r;
          float v = acc[i][j][r] + bb;
          if (MODE == 0)
            outB[(size_t)row * Ncols + col] = f2bf(v);
          else
            outF[(size_t)row * 128 + col] += v;
        }
      }
    }
  }
}

// ---------------- grouped GRU scan over T=512 — 1 chain/wave, K-split, bpermute h ----------------
// 512 blocks x 64 threads (1 wave, 1 chain). Lane (half=l>>5, d=l&31) computes the k-half
// [half*16, half*16+16) of the three gate dot-products for hidden dim d. 48 weights/lane.
// ROUND-4 EVIDENCE: with only __launch_bounds__(64,1) + asm pin the allocator SPILLED the pinned
// weights to scratch (VGPR_Count=52, FETCH +8MB, 1630 cyc/step). launch_bounds merely permits 512
// VGPRs; the backend's occupancy TARGET stayed high. amdgpu_waves_per_eu(1,1) sets the target
// itself (budget 512, pressure heuristics off) — the weights must now stay live.
// Halves merge via __shfl_xor(.,32); h broadcast is 16 ds_bpermute pulls (no LDS storage, no
// barriers, no lgkmcnt(0) turnaround on global prefetch).
__global__ __launch_bounds__(64, 1) __attribute__((amdgpu_waves_per_eu(1, 1)))
void gru_kernel(const unsigned short* __restrict__ xp,
                const float* __restrict__ whh,
                const float* __restrict__ bhh,
                float* __restrict__ seq) {
  const int l = threadIdx.x;
  const int half = l >> 5, d = l & 31;
  const int chain = blockIdx.x;         // 0..511
  const int n = chain >> 2, g = chain & 3;
  const int k0 = half * 16;

  // 48 weights: w[0..15]=whh_r[d][k0+j], w[16..31]=whh_z, w[32..47]=whh_n
  float w[48];
  #pragma unroll
  for (int u = 0; u < 4; ++u) {
    float4 a = *(const float4*)(whh + (size_t)d * 32 + k0 + u * 4);
    float4 b = *(const float4*)(whh + (size_t)(32 + d) * 32 + k0 + u * 4);
    float4 c = *(const float4*)(whh + (size_t)(64 + d) * 32 + k0 + u * 4);
    w[u * 4 + 0] = a.x;  w[u * 4 + 1] = a.y;  w[u * 4 + 2] = a.z;  w[u * 4 + 3] = a.w;
    w[16 + u * 4 + 0] = b.x; w[16 + u * 4 + 1] = b.y; w[16 + u * 4 + 2] = b.z; w[16 + u * 4 + 3] = b.w;
    w[32 + u * 4 + 0] = c.x; w[32 + u * 4 + 1] = c.y; w[32 + u * 4 + 2] = c.z; w[32 + u * 4 + 3] = c.w;
  }
  #pragma unroll
  for (int i = 0; i < 48; ++i) asm volatile("" : "+v"(w[i]));  // defeat remat

  const float br = bhh[d], bz = bhh[32 + d], bn = bhh[64 + d];

  // xp row for this chain at step t: xp[((n*512+t)*4+g)*96 + {d, 32+d, 64+d}]
  const unsigned short* xb = xp + ((size_t)(n * 512) * 4 + g) * 96;
  // seq target (lanes 0..31 store): seq[(n*512+t)*128 + g*32 + d]
  float* sb = seq + (size_t)(n * 512) * 128 + g * 32 + d;

  unsigned short pr[4], pz[4], pn[4];
  float psv[4];
  #pragma unroll
  for (int p = 0; p < 4; ++p) {
    const unsigned short* xr_ = xb + (size_t)p * 384;
    pr[p] = xr_[d]; pz[p] = xr_[32 + d]; pn[p] = xr_[64 + d];
    psv[p] = sb[(size_t)p * 128];
  }

  float hnew = 0.f;                 // lane's h_d (valid in lanes 0..31; upper half copy unused)
  const int pbase = half * 64;      // bpermute byte base: lower half pulls lanes 0..15, upper 16..31

  for (int t0 = 0; t0 < 512; t0 += 4) {
    #pragma unroll
    for (int p = 0; p < 4; ++p) {
      const int t = t0 + p;

      // broadcast h[k0+j] from lane (k0+j) (lower-half lanes hold h)
      float hj[16];
      #pragma unroll
      for (int j = 0; j < 16; ++j)
        hj[j] = __int_as_float(__builtin_amdgcn_ds_bpermute(pbase + 4 * j, __float_as_int(hnew)));

      float ar = 0.f, az = 0.f, an = 0.f;
      #pragma unroll
      for (int j = 0; j < 16; ++j) {
        ar = fmaf(w[j], hj[j], ar);
        az = fmaf(w[16 + j], hj[j], az);
        an = fmaf(w[32 + j], hj[j], an);
      }
      // merge k-halves (both halves end with the full sums)
      ar += __shfl_xor(ar, 32);
      az += __shfl_xor(az, 32);
      an += __shfl_xor(an, 32);
      float accr = ar + br, accz = az + bz, accn = an + bn;

      float xr = bf2f(pr[p]), xz = bf2f(pz[p]), xn = bf2f(pn[p]);
      float sv0 = psv[p];

      if (t + 4 < 512) {  // prefetch t+4 into slot p (stays in flight)
        const unsigned short* xr_ = xb + (size_t)(t + 4) * 384;
        pr[p] = xr_[d]; pz[p] = xr_[32 + d]; pn[p] = xr_[64 + d];
        psv[p] = sb[(size_t)(t + 4) * 128];
      }

      float r = 1.f / (1.f + __expf(-(xr + accr)));
      float z = 1.f / (1.f + __expf(-(xz + accz)));
      float e2 = __expf(2.f * (xn + r * accn));
      float nn = 1.f - 2.f / (e2 + 1.f);  // tanh, saturates cleanly at +/-1
      hnew = z * (hnew - nn) + nn;

      if (half == 0) sb[(size_t)t * 128] = sv0 + hnew;
    }
  }
}

// ---------------- windowed causal attention (scalar online softmax) ----------------
// grid (T/64=8, H=4, N=128), 128 threads = 32 q-pairs x 4 key-slices.
// qkv bf16 [n*512+t][384]: q @ h*32, k @ 128+h*32, v @ 256+h*32. out bf16 [n*512+t][128].
#define WCAP 164
__global__ __launch_bounds__(128) void attn_kernel(const unsigned short* __restrict__ qkv,
                                                   unsigned short* __restrict__ outp) {
  const int qbase = blockIdx.x * 64;
  const int h = blockIdx.y;
  const int n = blockIdx.z;
  const int tid = threadIdx.x;
  const int qp = tid >> 2, s = tid & 3;
  const int ws0 = max(0, qbase - 100);
  const int cnt = qbase + 64 - ws0;  // <= 164

  __shared__ unsigned int kl[WCAP * 20];
  __shared__ unsigned int vl[WCAP * 20];

  for (int i = tid; i < cnt * 16; i += 128) {
    int row = i >> 4, u = i & 15;
    size_t base = ((size_t)(n * 512 + ws0 + row)) * 384;
    kl[row * 20 + u] = ((const unsigned int*)(qkv + base + 128 + h * 32))[u];
    vl[row * 20 + u] = ((const unsigned int*)(qkv + base + 256 + h * 32))[u];
  }

  const int tqa = qbase + qp * 2, tqb = tqa + 1;
  float qv[2][32];
  {
    const unsigned int* qsa = (const unsigned int*)(qkv + ((size_t)(n * 512 + tqa)) * 384 + h * 32);
    const unsigned int* qsb = (const unsigned int*)(qkv + ((size_t)(n * 512 + tqb)) * 384 + h * 32);
    #pragma unroll
    for (int u = 0; u < 16; ++u) {
      unsigned int a = qsa[u], b = qsb[u];
      qv[0][2 * u] = bflo(a); qv[0][2 * u + 1] = bfhi(a);
      qv[1][2 * u] = bflo(b); qv[1][2 * u + 1] = bfhi(b);
    }
  }
  __syncthreads();

  float m[2] = {-INFINITY, -INFINITY}, l[2] = {0.f, 0.f};
  float o[2][32];
  #pragma unroll
  for (int d = 0; d < 32; ++d) { o[0][d] = 0.f; o[1][d] = 0.f; }

  const float scale = 0.17677669529663687f;  // 1/sqrt(32)
  const int iters = (cnt + 3) >> 2;

  for (int c = 0; c < iters; ++c) {
    int j = (c << 2) + s;
    int tk = ws0 + j;
    bool okv = (j < cnt);
    bool oka = okv && (tk <= tqa) && (tk + 100 >= tqa);
    bool okb = okv && (tk <= tqb) && (tk + 100 >= tqb);
    if (oka || okb) {
      float sa = 0.f, sb = 0.f;
      #pragma unroll
      for (int u = 0; u < 4; ++u) {
        uint4 kk = *(const uint4*)&kl[j * 20 + u * 4];
        float f0 = bflo(kk.x), f1 = bfhi(kk.x), f2 = bflo(kk.y), f3 = bfhi(kk.y);
        float f4 = bflo(kk.z), f5 = bfhi(kk.z), f6 = bflo(kk.w), f7 = bfhi(kk.w);
        int ee = u * 8;
        sa += qv[0][ee] * f0 + qv[0][ee + 1] * f1 + qv[0][ee + 2] * f2 + qv[0][ee + 3] * f3 +
              qv[0][ee + 4] * f4 + qv[0][ee + 5] * f5 + qv[0][ee + 6] * f6 + qv[0][ee + 7] * f7;
        sb += qv[1][ee] * f0 + qv[1][ee + 1] * f1 + qv[1][ee + 2] * f2 + qv[1][ee + 3] * f3 +
              qv[1][ee + 4] * f4 + qv[1][ee + 5] * f5 + qv[1][ee + 6] * f6 + qv[1][ee + 7] * f7;
      }
      sa *= scale; sb *= scale;
      float mna = oka ? fmaxf(m[0], sa) : m[0];
      float mnb = okb ? fmaxf(m[1], sb) : m[1];
      float ca = oka ? __expf(m[0] - mna) : 1.f;
      float cb = okb ? __expf(m[1] - mnb) : 1.f;
      float pa = oka ? __expf(sa - mna) : 0.f;
      float pb = okb ? __expf(sb - mnb) : 0.f;
      m[0] = mna; m[1] = mnb;
      l[0] = l[0] * ca + pa; l[1] = l[1] * cb + pb;
      #pragma unroll
      for (int u = 0; u < 4; ++u) {
        uint4 vvv = *(const uint4*)&vl[j * 20 + u * 4];
        float f0 = bflo(vvv.x), f1 = bfhi(vvv.x), f2 = bflo(vvv.y), f3 = bfhi(vvv.y);
        float f4 = bflo(vvv.z), f5 = bfhi(vvv.z), f6 = bflo(vvv.w), f7 = bfhi(vvv.w);
        int ee = u * 8;
        o[0][ee] = o[0][ee] * ca + pa * f0;       o[1][ee] = o[1][ee] * cb + pb * f0;
        o[0][ee + 1] = o[0][ee + 1] * ca + pa * f1; o[1][ee + 1] = o[1][ee + 1] * cb + pb * f1;
        o[0][ee + 2] = o[0][ee + 2] * ca + pa * f2; o[1][ee + 2] = o[1][ee + 2] * cb + pb * f2;
        o[0][ee + 3] = o[0][ee + 3] * ca + pa * f3; o[1][ee + 3] = o[1][ee + 3] * cb + pb * f3;
        o[0][ee + 4] = o[0][ee + 4] * ca + pa * f4; o[1][ee + 4] = o[1][ee + 4] * cb + pb * f4;
        o[0][ee + 5] = o[0][ee + 5] * ca + pa * f5; o[1][ee + 5] = o[1][ee + 5] * cb + pb * f5;
        o[0][ee + 6] = o[0][ee + 6] * ca + pa * f6; o[1][ee + 6] = o[1][ee + 6] * cb + pb * f6;
        o[0][ee + 7] = o[0][ee + 7] * ca + pa * f7; o[1][ee + 7] = o[1][ee + 7] * cb + pb * f7;
      }
    }
  }

  // merge the 4 key-slices (lanes 4*qp .. 4*qp+3, same wave) via shfl butterflies
  #pragma unroll
  for (int qi = 0; qi < 2; ++qi) {
    float mm = m[qi];
    mm = fmaxf(mm, __shfl_xor(mm, 1));
    mm = fmaxf(mm, __shfl_xor(mm, 2));
    float cr = __expf(m[qi] - mm);  // exp(-inf - finite) = 0 for empty slices
    float ll = l[qi] * cr;
    ll += __shfl_xor(ll, 1);
    ll += __shfl_xor(ll, 2);
    float rl = 1.f / ll;
    int tq = (qi == 0) ? tqa : tqb;
    size_t ob = ((size_t)(n * 512 + tq)) * 128 + h * 32;
    #pragma unroll
    for (int d = 0; d < 32; ++d) {
      float od = o[qi][d] * cr;
      od += __shfl_xor(od, 1);
      od += __shfl_xor(od, 2);
      if (s == 0) outp[ob + d] = f2bf(od * rl);
    }
  }
}

// ---------------- host launcher ----------------
extern "C" void kernel_launch(void* const* d_in, const int* in_sizes, int n_in,
                              void* d_out, int out_size, void* d_ws, size_t ws_size,
                              hipStream_t stream) {
  const float* x      = (const float*)d_in[0];
  const float* ln1_g  = (const float*)d_in[1];
  const float* ln1_b  = (const float*)d_in[2];
  const float* wih    = (const float*)d_in[3];
  const float* whh    = (const float*)d_in[4];
  const float* bih    = (const float*)d_in[5];
  const float* bhh    = (const float*)d_in[6];
  const float* ln2_g  = (const float*)d_in[7];
  const float* ln2_b  = (const float*)d_in[8];
  const float* inw    = (const float*)d_in[9];
  const float* inb    = (const float*)d_in[10];
  const float* outw   = (const float*)d_in[11];
  const float* outb   = (const float*)d_in[12];

  char* ws = (char*)d_ws;
  float*          seq   = (float*)ws;                             // 33,554,432 B
  unsigned short* tmpb  = (unsigned short*)(ws + 33554432);       // 16,777,216 B
  unsigned short* big   = (unsigned short*)(ws + 50331648);       // 50,331,648 B
  unsigned short* wih_b = (unsigned short*)(ws + 100663296);      // 3072 elems
  unsigned short* inw_b = wih_b + 3072;                           // 49152 elems
  unsigned short* outw_b = inw_b + 49152;                         // 16384 elems

  cvt_kernel<<<12, 256, 0, stream>>>(wih, wih_b, 3072);
  cvt_kernel<<<192, 256, 0, stream>>>(inw, inw_b, 49152);
  cvt_kernel<<<64, 256, 0, stream>>>(outw, outw_b, 16384);

  // x -> seq (residual stream)
  transpose_in_kernel<<<1024, 256, 0, stream>>>(x, seq);

  // ln1 -> tmpb (bf16), grouped view [262144][32]
  ln_kernel<<<16384, 256, 0, stream>>>(seq, ln1_g, ln1_b, tmpb);

  // GRU input projection: [262144][32] x [96][32]^T -> big [(n,t,g)][96]
  gemm_mfma<32, 0><<<dim3(2048, 1), 256, 0, stream>>>(tmpb, wih_b, bih, big, nullptr, 96);

  // GRU scan, seq += h_t  (1 chain per single-wave block)
  gru_kernel<<<512, 64, 0, stream>>>(big, whh, bhh, seq);

  // ln2 -> tmpb
  ln_kernel<<<16384, 256, 0, stream>>>(seq, ln2_g, ln2_b, tmpb);

  // QKV projection: [65536][128] x [384][128]^T -> big [65536][384]
  gemm_mfma<128, 0><<<dim3(512, 3), 256, 0, stream>>>(tmpb, inw_b, inb, big, nullptr, 384);

  // attention -> tmpb (bf16)
  attn_kernel<<<dim3(8, 4, 128), 128, 0, stream>>>(big, tmpb);

  // out projection, seq += attn @ Wo^T + bo
  gemm_mfma<128, 1><<<dim3(512, 1), 256, 0, stream>>>(tmpb, outw_b, outb, nullptr, seq, 128);

  // seq -> d_out
  transpose_out_kernel<<<1024, 256, 0, stream>>>(seq, (float*)d_out);
}

// Round 7
// 661.932 us; speedup vs baseline: 1.0371x; 1.0350x over previous
//
#include <hip/hip_runtime.h>
#include <hip/hip_bf16.h>
#include <math.h>

// Problem constants: B=2, C=128, T=512, F=64 -> N=B*F=128 sequences, NT=65536 rows.
// GRU: G=4 groups, D=32, 3D=96. MHA: H=4 heads, Dh=32, window=100.
// Workspace layout (needs ~100.8 MB):
//   seq  fp32 [65536][128]  @ 0          (33,554,432 B)  residual stream
//   tmpb bf16 [65536][128]  @ 33554432   (16,777,216 B)  ln1/ln2/attn-out
//   big  bf16 [65536][384]  @ 50331648   (50,331,648 B)  xp (grouped: [(n,t,g)][96]) then qkv
//   wbuf bf16 weights       @ 100663296  (~137 KB)

typedef __attribute__((ext_vector_type(8))) short short8;
typedef __attribute__((ext_vector_type(4))) float f32x4;
typedef _Float16 half2v __attribute__((ext_vector_type(2)));

__device__ __forceinline__ float bflo(unsigned int u) { return __uint_as_float(u << 16); }
__device__ __forceinline__ float bfhi(unsigned int u) { return __uint_as_float(u & 0xffff0000u); }
__device__ __forceinline__ float bf2f(unsigned short u) { return __uint_as_float(((unsigned int)u) << 16); }
__device__ __forceinline__ unsigned short f2bf(float f) {
  __hip_bfloat16 h = __float2bfloat16(f);
  return *reinterpret_cast<unsigned short*>(&h);
}
// cvt_pkrtz returns __fp16x2; bit_cast to our _Float16x2 (identical 4-byte layout)
__device__ __forceinline__ half2v pkrtz(float a, float b) {
  return __builtin_bit_cast(half2v, __builtin_amdgcn_cvt_pkrtz(a, b));
}

// ---------------- weight fp32 -> bf16 ----------------
__global__ void cvt_kernel(const float* __restrict__ s, unsigned short* __restrict__ d, int n) {
  int i = blockIdx.x * 256 + threadIdx.x;
  if (i < n) d[i] = f2bf(s[i]);
}

// ---------------- transpose x[B,C,T,F] -> seq[(b*64+f)][t][c] ----------------
__global__ __launch_bounds__(256) void transpose_in_kernel(const float* __restrict__ x, float* __restrict__ seq) {
  __shared__ float tile[128 * 65];
  int b = blockIdx.x >> 9;
  int t = blockIdx.x & 511;
  for (int i = threadIdx.x; i < 128 * 64; i += 256) {
    int c = i >> 6, f = i & 63;
    tile[c * 65 + f] = x[(((size_t)(b * 128 + c)) * 512 + t) * 64 + f];
  }
  __syncthreads();
  for (int i = threadIdx.x; i < 64 * 128; i += 256) {
    int f = i >> 7, c = i & 127;
    seq[(((size_t)(b * 64 + f)) * 512 + t) * 128 + c] = tile[c * 65 + f];
  }
}

__global__ __launch_bounds__(256) void transpose_out_kernel(const float* __restrict__ seq, float* __restrict__ out) {
  __shared__ float tile[128 * 65];
  int b = blockIdx.x >> 9;
  int t = blockIdx.x & 511;
  for (int i = threadIdx.x; i < 64 * 128; i += 256) {
    int f = i >> 7, c = i & 127;
    tile[c * 65 + f] = seq[(((size_t)(b * 64 + f)) * 512 + t) * 128 + c];
  }
  __syncthreads();
  for (int i = threadIdx.x; i < 128 * 64; i += 256) {
    int c = i >> 6, f = i & 63;
    out[(((size_t)(b * 128 + c)) * 512 + t) * 64 + f] = tile[c * 65 + f];
  }
}

// ---------------- layernorm over C=128, fp32 in -> bf16 out ----------------
__global__ __launch_bounds__(256) void ln_kernel(const float* __restrict__ in, const float* __restrict__ g,
                                                 const float* __restrict__ b, unsigned short* __restrict__ out) {
  int row = blockIdx.x * 4 + (threadIdx.x >> 6);
  int lane = threadIdx.x & 63;
  float2 v = ((const float2*)(in + (size_t)row * 128))[lane];
  float s = v.x + v.y, ss = v.x * v.x + v.y * v.y;
  #pragma unroll
  for (int off = 32; off > 0; off >>= 1) {
    s += __shfl_xor(s, off);
    ss += __shfl_xor(ss, off);
  }
  float mean = s * (1.f / 128.f);
  float var = ss * (1.f / 128.f) - mean * mean;
  float rs = rsqrtf(var + 1e-5f);
  float2 gg = ((const float2*)g)[lane];
  float2 bb = ((const float2*)b)[lane];
  float o0 = (v.x - mean) * rs * gg.x + bb.x;
  float o1 = (v.y - mean) * rs * gg.y + bb.y;
  unsigned int packed = ((unsigned int)f2bf(o1) << 16) | (unsigned int)f2bf(o0);
  ((unsigned int*)(out + (size_t)row * 128))[lane] = packed;
}

// ---------------- MFMA GEMM: out[m][n] (+)= sum_k A[m][k]*W[n][k] + bias[n] ----------------
// A bf16 [M][K] (M = gridDim.x*128), W bf16 [Ncols][K]. MODE 0: store bf16 (stride Ncols).
// MODE 1: outF[m*128+n] += v (fp32).
template <int K, int MODE>
__global__ __launch_bounds__(256) void gemm_mfma(const unsigned short* __restrict__ A,
                                                 const unsigned short* __restrict__ W,
                                                 const float* __restrict__ bias,
                                                 unsigned short* __restrict__ outB,
                                                 float* __restrict__ outF, int Ncols) {
  const int tid = threadIdx.x;
  const int wave = tid >> 6, lane = tid & 63;
  const int wy = wave >> 1, wx = wave & 1;
  const int lr = lane & 15, lq = lane >> 4;
  const int m0 = blockIdx.x * 128 + wy * 64;
  const int n0 = blockIdx.y * 128 + wx * 64;

  f32x4 acc[4][4];
  #pragma unroll
  for (int i = 0; i < 4; ++i)
    #pragma unroll
    for (int j = 0; j < 4; ++j) acc[i][j] = f32x4{0.f, 0.f, 0.f, 0.f};

  const short8 zfrag = short8{0, 0, 0, 0, 0, 0, 0, 0};

  #pragma unroll
  for (int kk = 0; kk < K; kk += 32) {
    short8 af[4], bfq[4];
    #pragma unroll
    for (int i = 0; i < 4; ++i)
      af[i] = *(const short8*)(A + (size_t)(m0 + i * 16 + lr) * K + kk + lq * 8);
    #pragma unroll
    for (int j = 0; j < 4; ++j) {
      int wr = n0 + j * 16 + lr;
      bfq[j] = (wr < Ncols) ? *(const short8*)(W + (size_t)wr * K + kk + lq * 8) : zfrag;
    }
    #pragma unroll
    for (int i = 0; i < 4; ++i)
      #pragma unroll
      for (int j = 0; j < 4; ++j)
        acc[i][j] = __builtin_amdgcn_mfma_f32_16x16x32_bf16(af[i], bfq[j], acc[i][j], 0, 0, 0);
  }

  #pragma unroll
  for (int j = 0; j < 4; ++j) {
    int col = n0 + j * 16 + lr;
    if (col < Ncols) {
      float bb = bias[col];
      #pragma unroll
      for (int i = 0; i < 4; ++i) {
        #pragma unroll
        for (int r = 0; r < 4; ++r) {
          int row = m0 + i * 16 + lq * 4 + r;
          float v = acc[i][j][r] + bb;
          if (MODE == 0)
            outB[(size_t)row * Ncols + col] = f2bf(v);
          else
            outF[(size_t)row * 128 + col] += v;
        }
      }
    }
  }
}

// ---------------- grouped GRU scan over T=512 — fp16 dot2, fits the allocator's budget --------
// ROUNDS 2-5 EVIDENCE: the backend pins this kernel's VGPR target at ~52 regardless of
// launch_bounds/asm-pin/waves_per_eu; 48 fp32 weights/lane ALWAYS end up in scratch with
// per-step reloads on the serial path (1630 cyc/step, FETCH 49MB vs 41MB true). So: make the
// working set FIT. Weights as 24 packed half2 (48 fp16) + v_dot2_f32_f16 -> ~58 VGPRs total.
// h broadcast = 8 ds_bpermute of packed h-pairs (repacked each step with one shfl_xor(1) +
// cvt_pkrtz). No LDS storage, no barriers, depth-4 global prefetch of xp/seq stays in flight.
__global__ __launch_bounds__(64) void gru_kernel(const unsigned short* __restrict__ xp,
                                                 const float* __restrict__ whh,
                                                 const float* __restrict__ bhh,
                                                 float* __restrict__ seq) {
  const int l = threadIdx.x;
  const int half = l >> 5, d = l & 31;
  const int chain = blockIdx.x;         // 0..511
  const int n = chain >> 2, g = chain & 3;
  const int k0 = half * 16;
  const int odd = l & 1;

  // 24 packed fp16 weight pairs: r: w2[0..7], z: w2[8..15], n: w2[16..23]; w2[q*8+j] covers
  // k = k0+2j, k0+2j+1 of gate q's row d.
  half2v w2[24];
  #pragma unroll
  for (int j = 0; j < 8; ++j) {
    float2 a = *(const float2*)(whh + (size_t)d * 32 + k0 + 2 * j);
    float2 b = *(const float2*)(whh + (size_t)(32 + d) * 32 + k0 + 2 * j);
    float2 c = *(const float2*)(whh + (size_t)(64 + d) * 32 + k0 + 2 * j);
    w2[j]      = pkrtz(a.x, a.y);
    w2[8 + j]  = pkrtz(b.x, b.y);
    w2[16 + j] = pkrtz(c.x, c.y);
  }
  const float br = bhh[d], bz = bhh[32 + d], bn = bhh[64 + d];

  // xp row for this chain at step t: xp[((n*512+t)*4+g)*96 + {d, 32+d, 64+d}]
  const unsigned short* xb = xp + ((size_t)(n * 512) * 4 + g) * 96;
  // seq target (lanes 0..31 store): seq[(n*512+t)*128 + g*32 + d]
  float* sb = seq + (size_t)(n * 512) * 128 + g * 32 + d;

  unsigned short pr[4], pz[4], pn[4];
  float psv[4];
  #pragma unroll
  for (int p = 0; p < 4; ++p) {
    const unsigned short* xr_ = xb + (size_t)p * 384;
    pr[p] = xr_[d]; pz[p] = xr_[32 + d]; pn[p] = xr_[64 + d];
    psv[p] = sb[(size_t)p * 128];
  }

  float hnew = 0.f;              // lane's h_d (replicated in both halves)
  int hpk = 0;                   // packed (h_{2p}, h_{2p+1}) fp16 pair, p = d>>1 — all lanes valid

  for (int t0 = 0; t0 < 512; t0 += 4) {
    #pragma unroll
    for (int p = 0; p < 4; ++p) {
      const int t = t0 + p;

      // gather the 8 packed h-pairs of this k-half and dot with fp16 weights
      float ar = 0.f, az = 0.f, an = 0.f;
      #pragma unroll
      for (int j = 0; j < 8; ++j) {
        int bits = __builtin_amdgcn_ds_bpermute((k0 + 2 * j) * 4, hpk);
        half2v h2 = __builtin_bit_cast(half2v, bits);
#if __has_builtin(__builtin_amdgcn_fdot2)
        ar = __builtin_amdgcn_fdot2(w2[j], h2, ar, false);
        az = __builtin_amdgcn_fdot2(w2[8 + j], h2, az, false);
        an = __builtin_amdgcn_fdot2(w2[16 + j], h2, an, false);
#else
        float h0 = (float)h2[0], h1 = (float)h2[1];
        ar = fmaf((float)w2[j][0], h0, fmaf((float)w2[j][1], h1, ar));
        az = fmaf((float)w2[8 + j][0], h0, fmaf((float)w2[8 + j][1], h1, az));
        an = fmaf((float)w2[16 + j][0], h0, fmaf((float)w2[16 + j][1], h1, an));
#endif
      }
      // merge k-halves (both halves end with full sums)
      ar += __shfl_xor(ar, 32);
      az += __shfl_xor(az, 32);
      an += __shfl_xor(an, 32);
      float accr = ar + br, accz = az + bz, accn = an + bn;

      float xr = bf2f(pr[p]), xz = bf2f(pz[p]), xn = bf2f(pn[p]);
      float sv0 = psv[p];

      if (t + 4 < 512) {  // prefetch t+4 into slot p (stays in flight)
        const unsigned short* xr_ = xb + (size_t)(t + 4) * 384;
        pr[p] = xr_[d]; pz[p] = xr_[32 + d]; pn[p] = xr_[64 + d];
        psv[p] = sb[(size_t)(t + 4) * 128];
      }

      float r = 1.f / (1.f + __expf(-(xr + accr)));
      float z = 1.f / (1.f + __expf(-(xz + accz)));
      float e2 = __expf(2.f * (xn + r * accn));
      float nn = 1.f - 2.f / (e2 + 1.f);  // tanh, saturates cleanly at +/-1
      hnew = z * (hnew - nn) + nn;

      // repack (h_even, h_odd) for next step's bpermute
      float hpart = __shfl_xor(hnew, 1);
      float lo = odd ? hpart : hnew;
      float hi = odd ? hnew : hpart;
      hpk = __builtin_bit_cast(int, pkrtz(lo, hi));

      if (half == 0) sb[(size_t)t * 128] = sv0 + hnew;
    }
  }
}

// ---------------- windowed causal attention (scalar online softmax) ----------------
// grid (T/64=8, H=4, N=128), 128 threads = 32 q-pairs x 4 key-slices.
// qkv bf16 [n*512+t][384]: q @ h*32, k @ 128+h*32, v @ 256+h*32. out bf16 [n*512+t][128].
#define WCAP 164
__global__ __launch_bounds__(128) void attn_kernel(const unsigned short* __restrict__ qkv,
                                                   unsigned short* __restrict__ outp) {
  const int qbase = blockIdx.x * 64;
  const int h = blockIdx.y;
  const int n = blockIdx.z;
  const int tid = threadIdx.x;
  const int qp = tid >> 2, s = tid & 3;
  const int ws0 = max(0, qbase - 100);
  const int cnt = qbase + 64 - ws0;  // <= 164

  __shared__ unsigned int kl[WCAP * 20];
  __shared__ unsigned int vl[WCAP * 20];

  for (int i = tid; i < cnt * 16; i += 128) {
    int row = i >> 4, u = i & 15;
    size_t base = ((size_t)(n * 512 + ws0 + row)) * 384;
    kl[row * 20 + u] = ((const unsigned int*)(qkv + base + 128 + h * 32))[u];
    vl[row * 20 + u] = ((const unsigned int*)(qkv + base + 256 + h * 32))[u];
  }

  const int tqa = qbase + qp * 2, tqb = tqa + 1;
  float qv[2][32];
  {
    const unsigned int* qsa = (const unsigned int*)(qkv + ((size_t)(n * 512 + tqa)) * 384 + h * 32);
    const unsigned int* qsb = (const unsigned int*)(qkv + ((size_t)(n * 512 + tqb)) * 384 + h * 32);
    #pragma unroll
    for (int u = 0; u < 16; ++u) {
      unsigned int a = qsa[u], b = qsb[u];
      qv[0][2 * u] = bflo(a); qv[0][2 * u + 1] = bfhi(a);
      qv[1][2 * u] = bflo(b); qv[1][2 * u + 1] = bfhi(b);
    }
  }
  __syncthreads();

  float m[2] = {-INFINITY, -INFINITY}, l[2] = {0.f, 0.f};
  float o[2][32];
  #pragma unroll
  for (int d = 0; d < 32; ++d) { o[0][d] = 0.f; o[1][d] = 0.f; }

  const float scale = 0.17677669529663687f;  // 1/sqrt(32)
  const int iters = (cnt + 3) >> 2;

  for (int c = 0; c < iters; ++c) {
    int j = (c << 2) + s;
    int tk = ws0 + j;
    bool okv = (j < cnt);
    bool oka = okv && (tk <= tqa) && (tk + 100 >= tqa);
    bool okb = okv && (tk <= tqb) && (tk + 100 >= tqb);
    if (oka || okb) {
      float sa = 0.f, sb = 0.f;
      #pragma unroll
      for (int u = 0; u < 4; ++u) {
        uint4 kk = *(const uint4*)&kl[j * 20 + u * 4];
        float f0 = bflo(kk.x), f1 = bfhi(kk.x), f2 = bflo(kk.y), f3 = bfhi(kk.y);
        float f4 = bflo(kk.z), f5 = bfhi(kk.z), f6 = bflo(kk.w), f7 = bfhi(kk.w);
        int ee = u * 8;
        sa += qv[0][ee] * f0 + qv[0][ee + 1] * f1 + qv[0][ee + 2] * f2 + qv[0][ee + 3] * f3 +
              qv[0][ee + 4] * f4 + qv[0][ee + 5] * f5 + qv[0][ee + 6] * f6 + qv[0][ee + 7] * f7;
        sb += qv[1][ee] * f0 + qv[1][ee + 1] * f1 + qv[1][ee + 2] * f2 + qv[1][ee + 3] * f3 +
              qv[1][ee + 4] * f4 + qv[1][ee + 5] * f5 + qv[1][ee + 6] * f6 + qv[1][ee + 7] * f7;
      }
      sa *= scale; sb *= scale;
      float mna = oka ? fmaxf(m[0], sa) : m[0];
      float mnb = okb ? fmaxf(m[1], sb) : m[1];
      float ca = oka ? __expf(m[0] - mna) : 1.f;
      float cb = okb ? __expf(m[1] - mnb) : 1.f;
      float pa = oka ? __expf(sa - mna) : 0.f;
      float pb = okb ? __expf(sb - mnb) : 0.f;
      m[0] = mna; m[1] = mnb;
      l[0] = l[0] * ca + pa; l[1] = l[1] * cb + pb;
      #pragma unroll
      for (int u = 0; u < 4; ++u) {
        uint4 vvv = *(const uint4*)&vl[j * 20 + u * 4];
        float f0 = bflo(vvv.x), f1 = bfhi(vvv.x), f2 = bflo(vvv.y), f3 = bfhi(vvv.y);
        float f4 = bflo(vvv.z), f5 = bfhi(vvv.z), f6 = bflo(vvv.w), f7 = bfhi(vvv.w);
        int ee = u * 8;
        o[0][ee] = o[0][ee] * ca + pa * f0;       o[1][ee] = o[1][ee] * cb + pb * f0;
        o[0][ee + 1] = o[0][ee + 1] * ca + pa * f1; o[1][ee + 1] = o[1][ee + 1] * cb + pb * f1;
        o[0][ee + 2] = o[0][ee + 2] * ca + pa * f2; o[1][ee + 2] = o[1][ee + 2] * cb + pb * f2;
        o[0][ee + 3] = o[0][ee + 3] * ca + pa * f3; o[1][ee + 3] = o[1][ee + 3] * cb + pb * f3;
        o[0][ee + 4] = o[0][ee + 4] * ca + pa * f4; o[1][ee + 4] = o[1][ee + 4] * cb + pb * f4;
        o[0][ee + 5] = o[0][ee + 5] * ca + pa * f5; o[1][ee + 5] = o[1][ee + 5] * cb + pb * f5;
        o[0][ee + 6] = o[0][ee + 6] * ca + pa * f6; o[1][ee + 6] = o[1][ee + 6] * cb + pb * f6;
        o[0][ee + 7] = o[0][ee + 7] * ca + pa * f7; o[1][ee + 7] = o[1][ee + 7] * cb + pb * f7;
      }
    }
  }

  // merge the 4 key-slices (lanes 4*qp .. 4*qp+3, same wave) via shfl butterflies
  #pragma unroll
  for (int qi = 0; qi < 2; ++qi) {
    float mm = m[qi];
    mm = fmaxf(mm, __shfl_xor(mm, 1));
    mm = fmaxf(mm, __shfl_xor(mm, 2));
    float cr = __expf(m[qi] - mm);  // exp(-inf - finite) = 0 for empty slices
    float ll = l[qi] * cr;
    ll += __shfl_xor(ll, 1);
    ll += __shfl_xor(ll, 2);
    float rl = 1.f / ll;
    int tq = (qi == 0) ? tqa : tqb;
    size_t ob = ((size_t)(n * 512 + tq)) * 128 + h * 32;
    #pragma unroll
    for (int d = 0; d < 32; ++d) {
      float od = o[qi][d] * cr;
      od += __shfl_xor(od, 1);
      od += __shfl_xor(od, 2);
      if (s == 0) outp[ob + d] = f2bf(od * rl);
    }
  }
}

// ---------------- host launcher ----------------
extern "C" void kernel_launch(void* const* d_in, const int* in_sizes, int n_in,
                              void* d_out, int out_size, void* d_ws, size_t ws_size,
                              hipStream_t stream) {
  const float* x      = (const float*)d_in[0];
  const float* ln1_g  = (const float*)d_in[1];
  const float* ln1_b  = (const float*)d_in[2];
  const float* wih    = (const float*)d_in[3];
  const float* whh    = (const float*)d_in[4];
  const float* bih    = (const float*)d_in[5];
  const float* bhh    = (const float*)d_in[6];
  const float* ln2_g  = (const float*)d_in[7];
  const float* ln2_b  = (const float*)d_in[8];
  const float* inw    = (const float*)d_in[9];
  const float* inb    = (const float*)d_in[10];
  const float* outw   = (const float*)d_in[11];
  const float* outb   = (const float*)d_in[12];

  char* ws = (char*)d_ws;
  float*          seq   = (float*)ws;                             // 33,554,432 B
  unsigned short* tmpb  = (unsigned short*)(ws + 33554432);       // 16,777,216 B
  unsigned short* big   = (unsigned short*)(ws + 50331648);       // 50,331,648 B
  unsigned short* wih_b = (unsigned short*)(ws + 100663296);      // 3072 elems
  unsigned short* inw_b = wih_b + 3072;                           // 49152 elems
  unsigned short* outw_b = inw_b + 49152;                         // 16384 elems

  cvt_kernel<<<12, 256, 0, stream>>>(wih, wih_b, 3072);
  cvt_kernel<<<192, 256, 0, stream>>>(inw, inw_b, 49152);
  cvt_kernel<<<64, 256, 0, stream>>>(outw, outw_b, 16384);

  // x -> seq (residual stream)
  transpose_in_kernel<<<1024, 256, 0, stream>>>(x, seq);

  // ln1 -> tmpb (bf16), grouped view [262144][32]
  ln_kernel<<<16384, 256, 0, stream>>>(seq, ln1_g, ln1_b, tmpb);

  // GRU input projection: [262144][32] x [96][32]^T -> big [(n,t,g)][96]
  gemm_mfma<32, 0><<<dim3(2048, 1), 256, 0, stream>>>(tmpb, wih_b, bih, big, nullptr, 96);

  // GRU scan, seq += h_t  (1 chain per single-wave block)
  gru_kernel<<<512, 64, 0, stream>>>(big, whh, bhh, seq);

  // ln2 -> tmpb
  ln_kernel<<<16384, 256, 0, stream>>>(seq, ln2_g, ln2_b, tmpb);

  // QKV projection: [65536][128] x [384][128]^T -> big [65536][384]
  gemm_mfma<128, 0><<<dim3(512, 3), 256, 0, stream>>>(tmpb, inw_b, inb, big, nullptr, 384);

  // attention -> tmpb (bf16)
  attn_kernel<<<dim3(8, 4, 128), 128, 0, stream>>>(big, tmpb);

  // out projection, seq += attn @ Wo^T + bo
  gemm_mfma<128, 1><<<dim3(512, 1), 256, 0, stream>>>(tmpb, outw_b, outb, nullptr, seq, 128);

  // seq -> d_out
  transpose_out_kernel<<<1024, 256, 0, stream>>>(seq, (float*)d_out);
}

// Round 8
// 648.606 us; speedup vs baseline: 1.0584x; 1.0205x over previous
//
#include <hip/hip_runtime.h>
#include <hip/hip_bf16.h>
#include <math.h>

// Problem constants: B=2, C=128, T=512, F=64 -> N=B*F=128 sequences, NT=65536 rows.
// GRU: G=4 groups, D=32, 3D=96. MHA: H=4 heads, Dh=32, window=100.
// Workspace layout (needs ~100.8 MB):
//   seq  fp32 [65536][128]  @ 0          (33,554,432 B)  residual stream
//   tmpb bf16 [65536][128]  @ 33554432   (16,777,216 B)  ln1/ln2/attn-out
//   big  bf16 [65536][384]  @ 50331648   (50,331,648 B)  xp (grouped: [(n,t,g)][96]) then qkv
//   wbuf bf16 weights       @ 100663296  (~137 KB)

typedef __attribute__((ext_vector_type(8))) short short8;
typedef __attribute__((ext_vector_type(4))) float f32x4;
typedef _Float16 half2v __attribute__((ext_vector_type(2)));

__device__ __forceinline__ float bflo(unsigned int u) { return __uint_as_float(u << 16); }
__device__ __forceinline__ float bfhi(unsigned int u) { return __uint_as_float(u & 0xffff0000u); }
__device__ __forceinline__ float bf2f(unsigned short u) { return __uint_as_float(((unsigned int)u) << 16); }
__device__ __forceinline__ unsigned short f2bf(float f) {
  __hip_bfloat16 h = __float2bfloat16(f);
  return *reinterpret_cast<unsigned short*>(&h);
}
// cvt_pkrtz returns __fp16x2; bit_cast to our _Float16x2 (identical 4-byte layout)
__device__ __forceinline__ half2v pkrtz(float a, float b) {
  return __builtin_bit_cast(half2v, __builtin_amdgcn_cvt_pkrtz(a, b));
}

// ---------------- weight fp32 -> bf16 ----------------
__global__ void cvt_kernel(const float* __restrict__ s, unsigned short* __restrict__ d, int n) {
  int i = blockIdx.x * 256 + threadIdx.x;
  if (i < n) d[i] = f2bf(s[i]);
}

// ---------------- transpose x[B,C,T,F] -> seq[(b*64+f)][t][c] ----------------
__global__ __launch_bounds__(256) void transpose_in_kernel(const float* __restrict__ x, float* __restrict__ seq) {
  __shared__ float tile[128 * 65];
  int b = blockIdx.x >> 9;
  int t = blockIdx.x & 511;
  for (int i = threadIdx.x; i < 128 * 64; i += 256) {
    int c = i >> 6, f = i & 63;
    tile[c * 65 + f] = x[(((size_t)(b * 128 + c)) * 512 + t) * 64 + f];
  }
  __syncthreads();
  for (int i = threadIdx.x; i < 64 * 128; i += 256) {
    int f = i >> 7, c = i & 127;
    seq[(((size_t)(b * 64 + f)) * 512 + t) * 128 + c] = tile[c * 65 + f];
  }
}

__global__ __launch_bounds__(256) void transpose_out_kernel(const float* __restrict__ seq, float* __restrict__ out) {
  __shared__ float tile[128 * 65];
  int b = blockIdx.x >> 9;
  int t = blockIdx.x & 511;
  for (int i = threadIdx.x; i < 64 * 128; i += 256) {
    int f = i >> 7, c = i & 127;
    tile[c * 65 + f] = seq[(((size_t)(b * 64 + f)) * 512 + t) * 128 + c];
  }
  __syncthreads();
  for (int i = threadIdx.x; i < 128 * 64; i += 256) {
    int c = i >> 6, f = i & 63;
    out[(((size_t)(b * 128 + c)) * 512 + t) * 64 + f] = tile[c * 65 + f];
  }
}

// ---------------- layernorm over C=128, fp32 in -> bf16 out ----------------
__global__ __launch_bounds__(256) void ln_kernel(const float* __restrict__ in, const float* __restrict__ g,
                                                 const float* __restrict__ b, unsigned short* __restrict__ out) {
  int row = blockIdx.x * 4 + (threadIdx.x >> 6);
  int lane = threadIdx.x & 63;
  float2 v = ((const float2*)(in + (size_t)row * 128))[lane];
  float s = v.x + v.y, ss = v.x * v.x + v.y * v.y;
  #pragma unroll
  for (int off = 32; off > 0; off >>= 1) {
    s += __shfl_xor(s, off);
    ss += __shfl_xor(ss, off);
  }
  float mean = s * (1.f / 128.f);
  float var = ss * (1.f / 128.f) - mean * mean;
  float rs = rsqrtf(var + 1e-5f);
  float2 gg = ((const float2*)g)[lane];
  float2 bb = ((const float2*)b)[lane];
  float o0 = (v.x - mean) * rs * gg.x + bb.x;
  float o1 = (v.y - mean) * rs * gg.y + bb.y;
  unsigned int packed = ((unsigned int)f2bf(o1) << 16) | (unsigned int)f2bf(o0);
  ((unsigned int*)(out + (size_t)row * 128))[lane] = packed;
}

// ---------------- MFMA GEMM: out[m][n] (+)= sum_k A[m][k]*W[n][k] + bias[n] ----------------
// A bf16 [M][K] (M = gridDim.x*128), W bf16 [Ncols][K]. MODE 0: store bf16 (stride Ncols).
// MODE 1: outF[m*128+n] += v (fp32).
template <int K, int MODE>
__global__ __launch_bounds__(256) void gemm_mfma(const unsigned short* __restrict__ A,
                                                 const unsigned short* __restrict__ W,
                                                 const float* __restrict__ bias,
                                                 unsigned short* __restrict__ outB,
                                                 float* __restrict__ outF, int Ncols) {
  const int tid = threadIdx.x;
  const int wave = tid >> 6, lane = tid & 63;
  const int wy = wave >> 1, wx = wave & 1;
  const int lr = lane & 15, lq = lane >> 4;
  const int m0 = blockIdx.x * 128 + wy * 64;
  const int n0 = blockIdx.y * 128 + wx * 64;

  f32x4 acc[4][4];
  #pragma unroll
  for (int i = 0; i < 4; ++i)
    #pragma unroll
    for (int j = 0; j < 4; ++j) acc[i][j] = f32x4{0.f, 0.f, 0.f, 0.f};

  const short8 zfrag = short8{0, 0, 0, 0, 0, 0, 0, 0};

  #pragma unroll
  for (int kk = 0; kk < K; kk += 32) {
    short8 af[4], bfq[4];
    #pragma unroll
    for (int i = 0; i < 4; ++i)
      af[i] = *(const short8*)(A + (size_t)(m0 + i * 16 + lr) * K + kk + lq * 8);
    #pragma unroll
    for (int j = 0; j < 4; ++j) {
      int wr = n0 + j * 16 + lr;
      bfq[j] = (wr < Ncols) ? *(const short8*)(W + (size_t)wr * K + kk + lq * 8) : zfrag;
    }
    #pragma unroll
    for (int i = 0; i < 4; ++i)
      #pragma unroll
      for (int j = 0; j < 4; ++j)
        acc[i][j] = __builtin_amdgcn_mfma_f32_16x16x32_bf16(af[i], bfq[j], acc[i][j], 0, 0, 0);
  }

  #pragma unroll
  for (int j = 0; j < 4; ++j) {
    int col = n0 + j * 16 + lr;
    if (col < Ncols) {
      float bb = bias[col];
      #pragma unroll
      for (int i = 0; i < 4; ++i) {
        #pragma unroll
        for (int r = 0; r < 4; ++r) {
          int row = m0 + i * 16 + lq * 4 + r;
          float v = acc[i][j][r] + bb;
          if (MODE == 0)
            outB[(size_t)row * Ncols + col] = f2bf(v);
          else
            outF[(size_t)row * 128 + col] += v;
        }
      }
    }
  }
}

// ---------------- grouped GRU scan over T=512 — LDS-staged xp, bpermute h, fp16 dot2 ---------
// ROUND-7 EVIDENCE killed the spill theory: weights resident (VGPR 44) yet still ~1500 cyc/step,
// FETCH unchanged. The constant across all variants is DEMAND GLOBAL LOADS of xp on the serial
// path — compiler vmcnt discipline makes each step eat an L2/L3 round trip (~1000 cyc). Fix:
// take global off the chain. Stage xp for 128 steps at a time into LDS (24 KB, coalesced uint4,
// 4 restages), read gate inputs via ds_read_u16 issued before the bpermutes (in-order lgkmcnt
// retirement = free). Remaining global ops (seq read+store) feed only the store -> off-chain.
// Chain/step: 8 bpermute + 24 fdot2 + 3 xor32 merges + gates ~= 400-450 cyc.
__global__ __launch_bounds__(64) void gru_kernel(const unsigned short* __restrict__ xp,
                                                 const float* __restrict__ whh,
                                                 const float* __restrict__ bhh,
                                                 float* __restrict__ seq) {
  const int l = threadIdx.x;
  const int half = l >> 5, d = l & 31;
  const int chain = blockIdx.x;         // 0..511
  const int n = chain >> 2, g = chain & 3;
  const int k0 = half * 16;
  const int odd = l & 1;

  __shared__ __align__(16) unsigned short xs[128 * 96];  // one 128-step segment of xp rows

  // 24 packed fp16 weight pairs: r: w2[0..7], z: w2[8..15], n: w2[16..23]
  half2v w2[24];
  #pragma unroll
  for (int j = 0; j < 8; ++j) {
    float2 a = *(const float2*)(whh + (size_t)d * 32 + k0 + 2 * j);
    float2 b = *(const float2*)(whh + (size_t)(32 + d) * 32 + k0 + 2 * j);
    float2 c = *(const float2*)(whh + (size_t)(64 + d) * 32 + k0 + 2 * j);
    w2[j]      = pkrtz(a.x, a.y);
    w2[8 + j]  = pkrtz(b.x, b.y);
    w2[16 + j] = pkrtz(c.x, c.y);
  }
  const float br = bhh[d], bz = bhh[32 + d], bn = bhh[64 + d];

  // xp row for this chain at step t: xb + t*384 shorts (96 contiguous shorts per row)
  const unsigned short* xb = xp + ((size_t)(n * 512) * 4 + g) * 96;
  // seq target (lanes 0..31 store): seq[(n*512+t)*128 + g*32 + d]
  float* sb = seq + (size_t)(n * 512) * 128 + g * 32 + d;

  float psv[4];
  #pragma unroll
  for (int p = 0; p < 4; ++p) psv[p] = sb[(size_t)p * 128];

  float hnew = 0.f;              // lane's h_d (replicated in both halves)
  int hpk = 0;                   // packed (h_{2p}, h_{2p+1}) fp16 pair at lanes 2p, 2p+1 (+32)

  for (int seg = 0; seg < 4; ++seg) {
    // ---- bulk stage 128 rows (24,576 B) of xp into LDS, fully coalesced uint4 ----
    {
      const int t0 = seg * 128;
      uint4* xsv = (uint4*)xs;
      #pragma unroll
      for (int k = 0; k < 24; ++k) {
        int j = l + k * 64;              // 0..1535
        int row = j / 12, u = j % 12;    // 12 uint4 per 96-short row
        xsv[j] = *((const uint4*)(xb + (size_t)(t0 + row) * 384) + u);
      }
    }
    __builtin_amdgcn_wave_barrier();  // single wave: pin staging before loop reads

    #pragma unroll 4
    for (int tt = 0; tt < 128; ++tt) {
      const int t = seg * 128 + tt;

      // gate inputs from LDS — issue before bpermutes (in-order lgkm retire = free)
      unsigned short xr16 = xs[tt * 96 + d];
      unsigned short xz16 = xs[tt * 96 + 32 + d];
      unsigned short xn16 = xs[tt * 96 + 64 + d];

      // gather the 8 packed h-pairs of this k-half and dot with fp16 weights
      float ar = 0.f, az = 0.f, an = 0.f;
      #pragma unroll
      for (int j = 0; j < 8; ++j) {
        int bits = __builtin_amdgcn_ds_bpermute((k0 + 2 * j) * 4, hpk);
        half2v h2 = __builtin_bit_cast(half2v, bits);
#if __has_builtin(__builtin_amdgcn_fdot2)
        ar = __builtin_amdgcn_fdot2(w2[j], h2, ar, false);
        az = __builtin_amdgcn_fdot2(w2[8 + j], h2, az, false);
        an = __builtin_amdgcn_fdot2(w2[16 + j], h2, an, false);
#else
        float h0 = (float)h2[0], h1 = (float)h2[1];
        ar = fmaf((float)w2[j][0], h0, fmaf((float)w2[j][1], h1, ar));
        az = fmaf((float)w2[8 + j][0], h0, fmaf((float)w2[8 + j][1], h1, az));
        an = fmaf((float)w2[16 + j][0], h0, fmaf((float)w2[16 + j][1], h1, an));
#endif
      }
      // merge k-halves (both halves end with full sums)
      ar += __shfl_xor(ar, 32);
      az += __shfl_xor(az, 32);
      an += __shfl_xor(an, 32);
      float accr = ar + br, accz = az + bz, accn = an + bn;

      float xr = bf2f(xr16), xz = bf2f(xz16), xn = bf2f(xn16);
      float sv0 = psv[t & 3];
      if (t + 4 < 512) psv[t & 3] = sb[(size_t)(t + 4) * 128];  // off-chain seq prefetch

      float r = 1.f / (1.f + __expf(-(xr + accr)));
      float z = 1.f / (1.f + __expf(-(xz + accz)));
      float e2 = __expf(2.f * (xn + r * accn));
      float nn = 1.f - 2.f / (e2 + 1.f);  // tanh, saturates cleanly at +/-1
      hnew = z * (hnew - nn) + nn;

      // repack (h_even, h_odd) for next step's bpermute (xor 1 = cheap DPP)
      float hpart = __shfl_xor(hnew, 1);
      float lo = odd ? hpart : hnew;
      float hi = odd ? hnew : hpart;
      hpk = __builtin_bit_cast(int, pkrtz(lo, hi));

      if (half == 0) sb[(size_t)t * 128] = sv0 + hnew;
    }
    __builtin_amdgcn_wave_barrier();  // keep next segment's staging after this loop
  }
}

// ---------------- windowed causal attention (scalar online softmax) ----------------
// grid (T/64=8, H=4, N=128), 128 threads = 32 q-pairs x 4 key-slices.
// qkv bf16 [n*512+t][384]: q @ h*32, k @ 128+h*32, v @ 256+h*32. out bf16 [n*512+t][128].
#define WCAP 164
__global__ __launch_bounds__(128) void attn_kernel(const unsigned short* __restrict__ qkv,
                                                   unsigned short* __restrict__ outp) {
  const int qbase = blockIdx.x * 64;
  const int h = blockIdx.y;
  const int n = blockIdx.z;
  const int tid = threadIdx.x;
  const int qp = tid >> 2, s = tid & 3;
  const int ws0 = max(0, qbase - 100);
  const int cnt = qbase + 64 - ws0;  // <= 164

  __shared__ unsigned int kl[WCAP * 20];
  __shared__ unsigned int vl[WCAP * 20];

  for (int i = tid; i < cnt * 16; i += 128) {
    int row = i >> 4, u = i & 15;
    size_t base = ((size_t)(n * 512 + ws0 + row)) * 384;
    kl[row * 20 + u] = ((const unsigned int*)(qkv + base + 128 + h * 32))[u];
    vl[row * 20 + u] = ((const unsigned int*)(qkv + base + 256 + h * 32))[u];
  }

  const int tqa = qbase + qp * 2, tqb = tqa + 1;
  float qv[2][32];
  {
    const unsigned int* qsa = (const unsigned int*)(qkv + ((size_t)(n * 512 + tqa)) * 384 + h * 32);
    const unsigned int* qsb = (const unsigned int*)(qkv + ((size_t)(n * 512 + tqb)) * 384 + h * 32);
    #pragma unroll
    for (int u = 0; u < 16; ++u) {
      unsigned int a = qsa[u], b = qsb[u];
      qv[0][2 * u] = bflo(a); qv[0][2 * u + 1] = bfhi(a);
      qv[1][2 * u] = bflo(b); qv[1][2 * u + 1] = bfhi(b);
    }
  }
  __syncthreads();

  float m[2] = {-INFINITY, -INFINITY}, l[2] = {0.f, 0.f};
  float o[2][32];
  #pragma unroll
  for (int d = 0; d < 32; ++d) { o[0][d] = 0.f; o[1][d] = 0.f; }

  const float scale = 0.17677669529663687f;  // 1/sqrt(32)
  const int iters = (cnt + 3) >> 2;

  for (int c = 0; c < iters; ++c) {
    int j = (c << 2) + s;
    int tk = ws0 + j;
    bool okv = (j < cnt);
    bool oka = okv && (tk <= tqa) && (tk + 100 >= tqa);
    bool okb = okv && (tk <= tqb) && (tk + 100 >= tqb);
    if (oka || okb) {
      float sa = 0.f, sb = 0.f;
      #pragma unroll
      for (int u = 0; u < 4; ++u) {
        uint4 kk = *(const uint4*)&kl[j * 20 + u * 4];
        float f0 = bflo(kk.x), f1 = bfhi(kk.x), f2 = bflo(kk.y), f3 = bfhi(kk.y);
        float f4 = bflo(kk.z), f5 = bfhi(kk.z), f6 = bflo(kk.w), f7 = bfhi(kk.w);
        int ee = u * 8;
        sa += qv[0][ee] * f0 + qv[0][ee + 1] * f1 + qv[0][ee + 2] * f2 + qv[0][ee + 3] * f3 +
              qv[0][ee + 4] * f4 + qv[0][ee + 5] * f5 + qv[0][ee + 6] * f6 + qv[0][ee + 7] * f7;
        sb += qv[1][ee] * f0 + qv[1][ee + 1] * f1 + qv[1][ee + 2] * f2 + qv[1][ee + 3] * f3 +
              qv[1][ee + 4] * f4 + qv[1][ee + 5] * f5 + qv[1][ee + 6] * f6 + qv[1][ee + 7] * f7;
      }
      sa *= scale; sb *= scale;
      float mna = oka ? fmaxf(m[0], sa) : m[0];
      float mnb = okb ? fmaxf(m[1], sb) : m[1];
      float ca = oka ? __expf(m[0] - mna) : 1.f;
      float cb = okb ? __expf(m[1] - mnb) : 1.f;
      float pa = oka ? __expf(sa - mna) : 0.f;
      float pb = okb ? __expf(sb - mnb) : 0.f;
      m[0] = mna; m[1] = mnb;
      l[0] = l[0] * ca + pa; l[1] = l[1] * cb + pb;
      #pragma unroll
      for (int u = 0; u < 4; ++u) {
        uint4 vvv = *(const uint4*)&vl[j * 20 + u * 4];
        float f0 = bflo(vvv.x), f1 = bfhi(vvv.x), f2 = bflo(vvv.y), f3 = bfhi(vvv.y);
        float f4 = bflo(vvv.z), f5 = bfhi(vvv.z), f6 = bflo(vvv.w), f7 = bfhi(vvv.w);
        int ee = u * 8;
        o[0][ee] = o[0][ee] * ca + pa * f0;       o[1][ee] = o[1][ee] * cb + pb * f0;
        o[0][ee + 1] = o[0][ee + 1] * ca + pa * f1; o[1][ee + 1] = o[1][ee + 1] * cb + pb * f1;
        o[0][ee + 2] = o[0][ee + 2] * ca + pa * f2; o[1][ee + 2] = o[1][ee + 2] * cb + pb * f2;
        o[0][ee + 3] = o[0][ee + 3] * ca + pa * f3; o[1][ee + 3] = o[1][ee + 3] * cb + pb * f3;
        o[0][ee + 4] = o[0][ee + 4] * ca + pa * f4; o[1][ee + 4] = o[1][ee + 4] * cb + pb * f4;
        o[0][ee + 5] = o[0][ee + 5] * ca + pa * f5; o[1][ee + 5] = o[1][ee + 5] * cb + pb * f5;
        o[0][ee + 6] = o[0][ee + 6] * ca + pa * f6; o[1][ee + 6] = o[1][ee + 6] * cb + pb * f6;
        o[0][ee + 7] = o[0][ee + 7] * ca + pa * f7; o[1][ee + 7] = o[1][ee + 7] * cb + pb * f7;
      }
    }
  }

  // merge the 4 key-slices (lanes 4*qp .. 4*qp+3, same wave) via shfl butterflies
  #pragma unroll
  for (int qi = 0; qi < 2; ++qi) {
    float mm = m[qi];
    mm = fmaxf(mm, __shfl_xor(mm, 1));
    mm = fmaxf(mm, __shfl_xor(mm, 2));
    float cr = __expf(m[qi] - mm);  // exp(-inf - finite) = 0 for empty slices
    float ll = l[qi] * cr;
    ll += __shfl_xor(ll, 1);
    ll += __shfl_xor(ll, 2);
    float rl = 1.f / ll;
    int tq = (qi == 0) ? tqa : tqb;
    size_t ob = ((size_t)(n * 512 + tq)) * 128 + h * 32;
    #pragma unroll
    for (int d = 0; d < 32; ++d) {
      float od = o[qi][d] * cr;
      od += __shfl_xor(od, 1);
      od += __shfl_xor(od, 2);
      if (s == 0) outp[ob + d] = f2bf(od * rl);
    }
  }
}

// ---------------- host launcher ----------------
extern "C" void kernel_launch(void* const* d_in, const int* in_sizes, int n_in,
                              void* d_out, int out_size, void* d_ws, size_t ws_size,
                              hipStream_t stream) {
  const float* x      = (const float*)d_in[0];
  const float* ln1_g  = (const float*)d_in[1];
  const float* ln1_b  = (const float*)d_in[2];
  const float* wih    = (const float*)d_in[3];
  const float* whh    = (const float*)d_in[4];
  const float* bih    = (const float*)d_in[5];
  const float* bhh    = (const float*)d_in[6];
  const float* ln2_g  = (const float*)d_in[7];
  const float* ln2_b  = (const float*)d_in[8];
  const float* inw    = (const float*)d_in[9];
  const float* inb    = (const float*)d_in[10];
  const float* outw   = (const float*)d_in[11];
  const float* outb   = (const float*)d_in[12];

  char* ws = (char*)d_ws;
  float*          seq   = (float*)ws;                             // 33,554,432 B
  unsigned short* tmpb  = (unsigned short*)(ws + 33554432);       // 16,777,216 B
  unsigned short* big   = (unsigned short*)(ws + 50331648);       // 50,331,648 B
  unsigned short* wih_b = (unsigned short*)(ws + 100663296);      // 3072 elems
  unsigned short* inw_b = wih_b + 3072;                           // 49152 elems
  unsigned short* outw_b = inw_b + 49152;                         // 16384 elems

  cvt_kernel<<<12, 256, 0, stream>>>(wih, wih_b, 3072);
  cvt_kernel<<<192, 256, 0, stream>>>(inw, inw_b, 49152);
  cvt_kernel<<<64, 256, 0, stream>>>(outw, outw_b, 16384);

  // x -> seq (residual stream)
  transpose_in_kernel<<<1024, 256, 0, stream>>>(x, seq);

  // ln1 -> tmpb (bf16), grouped view [262144][32]
  ln_kernel<<<16384, 256, 0, stream>>>(seq, ln1_g, ln1_b, tmpb);

  // GRU input projection: [262144][32] x [96][32]^T -> big [(n,t,g)][96]
  gemm_mfma<32, 0><<<dim3(2048, 1), 256, 0, stream>>>(tmpb, wih_b, bih, big, nullptr, 96);

  // GRU scan, seq += h_t  (1 chain per single-wave block, LDS-staged xp)
  gru_kernel<<<512, 64, 0, stream>>>(big, whh, bhh, seq);

  // ln2 -> tmpb
  ln_kernel<<<16384, 256, 0, stream>>>(seq, ln2_g, ln2_b, tmpb);

  // QKV projection: [65536][128] x [384][128]^T -> big [65536][384]
  gemm_mfma<128, 0><<<dim3(512, 3), 256, 0, stream>>>(tmpb, inw_b, inb, big, nullptr, 384);

  // attention -> tmpb (bf16)
  attn_kernel<<<dim3(8, 4, 128), 128, 0, stream>>>(big, tmpb);

  // out projection, seq += attn @ Wo^T + bo
  gemm_mfma<128, 1><<<dim3(512, 1), 256, 0, stream>>>(tmpb, outw_b, outb, nullptr, seq, 128);

  // seq -> d_out
  transpose_out_kernel<<<1024, 256, 0, stream>>>(seq, (float*)d_out);
}